// Round 11
// baseline (269.172 us; speedup 1.0000x reference)
//
#include <hip/hip_runtime.h>
#include <hip/hip_bf16.h>
#include <math.h>

#define N_NODES 50000
#define N_EDGES 800000
#define IN_CH 128
#define OUT_CH 64
#define BN_EPS 1e-5f
#define NB_ALLOC 196   // ceil(50000/256)
#define NB_WFRAG 32    // 32*256 = 8192 = W element count

typedef __attribute__((ext_vector_type(8))) short short8;
typedef __attribute__((ext_vector_type(4))) float f32x4;

__device__ __forceinline__ float bf16u_to_f32(uint u) { return __uint_as_float(u << 16); }

__device__ __forceinline__ ushort f32_to_bf16(float f) {
    uint u = __float_as_uint(f);
    uint r = (u + 0x7fff + ((u >> 16) & 1)) >> 16;  // RNE
    return (ushort)r;
}

// ---------------- degree count over edge dst (int4 reads, int atomics) ----------------
__global__ void count_kernel(const int4* __restrict__ edst4, int* __restrict__ cnt, int E4) {
    int i = blockIdx.x * blockDim.x + threadIdx.x;
    if (i < E4) {
        int4 d = edst4[i];
        atomicAdd(&cnt[d.x], 1);
        atomicAdd(&cnt[d.y], 1);
        atomicAdd(&cnt[d.z], 1);
        atomicAdd(&cnt[d.w], 1);
    }
}

// ---------------- alloc (blocks 0..195): block scan + 1 global atomic -> offsets/cursor/dinv/sums
// ---------------- wfrag (blocks 196..227): W -> bf16 MFMA B-fragment layout ----------------
// wbuf element e: frag f=e>>3, j=e&7; lane=f&63, c=(f>>6)&3, t2=f>>8;
// value = W[(32c + 8*(lane>>4) + j)*64 + 16*t2 + (lane&15)]
__global__ __launch_bounds__(256) void alloc_kernel(const int* __restrict__ cnt,
                                                    int* __restrict__ gcur,
                                                    int* __restrict__ offsets,
                                                    int* __restrict__ cursor,
                                                    float* __restrict__ dinv,
                                                    float* __restrict__ sums,
                                                    const float* __restrict__ W,
                                                    ushort* __restrict__ wbuf, int N) {
    int t = threadIdx.x;
    if (blockIdx.x >= NB_ALLOC) {
        int e = (blockIdx.x - NB_ALLOC) * 256 + t;
        int f = e >> 3, j = e & 7;
        int lane = f & 63, c = (f >> 6) & 3, t2 = f >> 8;
        int k = 32 * c + 8 * (lane >> 4) + j;
        int n = 16 * t2 + (lane & 15);
        wbuf[e] = f32_to_bf16(W[k * 64 + n]);
        return;
    }
    __shared__ int ls[256];
    __shared__ int sbase;
    int i = blockIdx.x * 256 + t;
    int c = (i < N) ? cnt[i] : 0;
    ls[t] = c;
    __syncthreads();
    for (int off = 1; off < 256; off <<= 1) {
        int u = (t >= off) ? ls[t - off] : 0;
        __syncthreads();
        ls[t] += u;
        __syncthreads();
    }
    if (t == 255) sbase = atomicAdd(gcur, ls[255]);
    __syncthreads();
    if (i < N) {
        int excl = ls[t] - c + sbase;
        offsets[i] = excl;
        cursor[i] = excl;
        dinv[i] = rsqrtf((float)(c + 1));  // +1 self-loop
    }
    if (blockIdx.x == 0 && t < 128) sums[t] = 0.0f;
}

// ---------------- fill buckets: bucket[pos] = src (ushort) ----------------
__global__ void fill_kernel(const int4* __restrict__ esrc4, const int4* __restrict__ edst4,
                            int* __restrict__ cursor, ushort* __restrict__ bucket, int E4) {
    int i = blockIdx.x * blockDim.x + threadIdx.x;
    if (i < E4) {
        int4 s = esrc4[i];
        int4 d = edst4[i];
        int p;
        p = atomicAdd(&cursor[d.x], 1); bucket[p] = (ushort)s.x;
        p = atomicAdd(&cursor[d.y], 1); bucket[p] = (ushort)s.y;
        p = atomicAdd(&cursor[d.z], 1); bucket[p] = (ushort)s.z;
        p = atomicAdd(&cursor[d.w], 1); bucket[p] = (ushort)s.w;
    }
}

// ---------------- LDS-free MFMA GEMM: hb[N,64](bf16) = bf16(x[N,128]) @ wbuf ----------------
// Block = 256 thr (4 waves), 64 rows. Wave w: rows row0+16w+nn (nn=lane&15), quad=lane>>4.
// A-frag: x[(row)*128 + 32c + 8*quad .. +7] as two float4 -> 8 bf16 in regs.
// B-frag: wbuf fragment layout (precomputed in alloc_kernel).
__global__ __launch_bounds__(256) void gemm_mfma_kernel(const float* __restrict__ x,
                                                        const ushort* __restrict__ wbuf,
                                                        ushort* __restrict__ hb, int N) {
    int t = threadIdx.x;
    int lane = t & 63;
    int w = t >> 6;
    int nn = lane & 15;
    int quad = lane >> 4;
    int row = blockIdx.x * 64 + 16 * w + nn;   // the M-row this lane owns
    int rowc = row < N ? row : N - 1;          // clamp for loads

    // B fragments: bfrag[t2][c] at wbuf[((t2*4+c)*64+lane)*8], coalesced 16B/lane
    short8 bfrag[4][4];
#pragma unroll
    for (int t2 = 0; t2 < 4; ++t2)
#pragma unroll
        for (int c = 0; c < 4; ++c)
            bfrag[t2][c] = *(const short8*)&wbuf[(((t2 * 4 + c) * 64) + lane) * 8];

    f32x4 acc[4] = {{0.f, 0.f, 0.f, 0.f}, {0.f, 0.f, 0.f, 0.f},
                    {0.f, 0.f, 0.f, 0.f}, {0.f, 0.f, 0.f, 0.f}};
    const float* xrow = x + (size_t)rowc * IN_CH;
#pragma unroll
    for (int c = 0; c < 4; ++c) {
        float4 v0 = *(const float4*)(xrow + 32 * c + 8 * quad);
        float4 v1 = *(const float4*)(xrow + 32 * c + 8 * quad + 4);
        short8 afrag;
        afrag[0] = (short)f32_to_bf16(v0.x); afrag[1] = (short)f32_to_bf16(v0.y);
        afrag[2] = (short)f32_to_bf16(v0.z); afrag[3] = (short)f32_to_bf16(v0.w);
        afrag[4] = (short)f32_to_bf16(v1.x); afrag[5] = (short)f32_to_bf16(v1.y);
        afrag[6] = (short)f32_to_bf16(v1.z); afrag[7] = (short)f32_to_bf16(v1.w);
#pragma unroll
        for (int t2 = 0; t2 < 4; ++t2)
            acc[t2] = __builtin_amdgcn_mfma_f32_16x16x32_bf16(afrag, bfrag[t2][c], acc[t2], 0, 0, 0);
    }

    // D layout: col = 16*t2 + nn, row = block row0 + 16w + quad*4 + r
    int orow0 = blockIdx.x * 64 + 16 * w + quad * 4;
#pragma unroll
    for (int t2 = 0; t2 < 4; ++t2) {
#pragma unroll
        for (int r = 0; r < 4; ++r) {
            int orow = orow0 + r;
            if (orow < N) hb[(size_t)orow * OUT_CH + 16 * t2 + nn] = f32_to_bf16(acc[t2][r]);
        }
    }
}

// ---------------- fused gather: R6 structure, plain ushort bucket ----------------
// One wave per dst node; lane = channel. Row index via uniform shfl -> scalar-base loads.
__global__ __launch_bounds__(256) void gather_fused_kernel(const int* __restrict__ cnt,
                                                           const int* __restrict__ offsets,
                                                           const ushort* __restrict__ bucket,
                                                           const float* __restrict__ dinv,
                                                           const ushort* __restrict__ hb,
                                                           const float* __restrict__ bias,
                                                           float* __restrict__ out,
                                                           float* __restrict__ sums, int N) {
    int t = threadIdx.x;
    int lane = t & 63;
    int wid = (blockIdx.x * blockDim.x + t) >> 6;
    int nw = (gridDim.x * blockDim.x) >> 6;
    float bias_c = bias[lane];
    float ssum = 0.f, ssq = 0.f;

    for (int d = wid; d < N; d += nw) {
        float dd = dinv[d];
        float acc = bf16u_to_f32(hb[(size_t)d * OUT_CH + lane]) * dd * dd;  // self-loop
        int b0 = offsets[d];
        int b1 = b0 + cnt[d];
        for (int base = b0; base < b1; base += 64) {
            int idx = base + lane;
            int sv = 0; float dv = 0.f;
            if (idx < b1) { sv = bucket[idx]; dv = dinv[sv]; }  // plain load: stays cacheable
            int m = b1 - base; if (m > 64) m = 64;
            int j = 0;
            for (; j + 3 < m; j += 4) {  // 4-deep ILP, wave-uniform shfl index
                int s0 = __shfl(sv, j + 0); float w0 = __shfl(dv, j + 0);
                int s1 = __shfl(sv, j + 1); float w1 = __shfl(dv, j + 1);
                int s2 = __shfl(sv, j + 2); float w2 = __shfl(dv, j + 2);
                int s3 = __shfl(sv, j + 3); float w3 = __shfl(dv, j + 3);
                uint h0 = hb[(size_t)s0 * OUT_CH + lane];
                uint h1 = hb[(size_t)s1 * OUT_CH + lane];
                uint h2 = hb[(size_t)s2 * OUT_CH + lane];
                uint h3 = hb[(size_t)s3 * OUT_CH + lane];
                acc += bf16u_to_f32(h0) * (w0 * dd);
                acc += bf16u_to_f32(h1) * (w1 * dd);
                acc += bf16u_to_f32(h2) * (w2 * dd);
                acc += bf16u_to_f32(h3) * (w3 * dd);
            }
            for (; j < m; ++j) {
                int s = __shfl(sv, j);
                float ww = __shfl(dv, j) * dd;
                acc += bf16u_to_f32(hb[(size_t)s * OUT_CH + lane]) * ww;
            }
        }
        float v = tanhf(acc + bias_c);
        out[(size_t)d * OUT_CH + lane] = v;
        ssum += v;
        ssq += v * v;
    }

    __shared__ float ls[256];
    __shared__ float ls2[256];
    ls[t] = ssum; ls2[t] = ssq;
    __syncthreads();
    if (t < 128) { ls[t] += ls[t + 128]; ls2[t] += ls2[t + 128]; }
    __syncthreads();
    if (t < 64) {
        atomicAdd(&sums[t], ls[t] + ls[t + 64]);
        atomicAdd(&sums[64 + t], ls2[t] + ls2[t + 64]);
    }
}

// ---------------- BN apply in place (float4) ----------------
__global__ __launch_bounds__(256) void bn_apply_kernel(float4* __restrict__ a,
                                                       const float* __restrict__ sums,
                                                       const float* __restrict__ gamma,
                                                       const float* __restrict__ beta, int total4) {
    int c0 = (threadIdx.x * 4) & 63;
    const float invN = 1.0f / (float)N_NODES;
    float4 scale, shift;
    {
        float m0 = sums[c0 + 0] * invN, m1 = sums[c0 + 1] * invN;
        float m2 = sums[c0 + 2] * invN, m3 = sums[c0 + 3] * invN;
        float v0 = sums[64 + c0 + 0] * invN - m0 * m0;
        float v1 = sums[64 + c0 + 1] * invN - m1 * m1;
        float v2 = sums[64 + c0 + 2] * invN - m2 * m2;
        float v3 = sums[64 + c0 + 3] * invN - m3 * m3;
        scale.x = gamma[c0 + 0] * rsqrtf(v0 + BN_EPS);
        scale.y = gamma[c0 + 1] * rsqrtf(v1 + BN_EPS);
        scale.z = gamma[c0 + 2] * rsqrtf(v2 + BN_EPS);
        scale.w = gamma[c0 + 3] * rsqrtf(v3 + BN_EPS);
        shift.x = beta[c0 + 0] - m0 * scale.x;
        shift.y = beta[c0 + 1] - m1 * scale.y;
        shift.z = beta[c0 + 2] - m2 * scale.z;
        shift.w = beta[c0 + 3] - m3 * scale.w;
    }
    int stride = gridDim.x * blockDim.x;
    for (int idx = blockIdx.x * blockDim.x + threadIdx.x; idx < total4; idx += stride) {
        float4 v = a[idx];
        v.x = v.x * scale.x + shift.x;
        v.y = v.y * scale.y + shift.y;
        v.z = v.z * scale.z + shift.z;
        v.w = v.w * scale.w + shift.w;
        a[idx] = v;
    }
}

extern "C" void kernel_launch(void* const* d_in, const int* in_sizes, int n_in,
                              void* d_out, int out_size, void* d_ws, size_t ws_size,
                              hipStream_t stream) {
    const float* x     = (const float*)d_in[0];
    const int*   eidx  = (const int*)d_in[1];   // [2, E] flat: src row then dst row
    const float* W     = (const float*)d_in[2];
    const float* bias  = (const float*)d_in[3];
    const float* gamma = (const float*)d_in[4];
    const float* beta  = (const float*)d_in[5];
    float* out = (float*)d_out;

    const int4* esrc4 = (const int4*)eidx;
    const int4* edst4 = (const int4*)(eidx + N_EDGES);
    const int E4 = N_EDGES / 4;

    // workspace layout:
    // hb ushort[N*64] (6.4MB) | cnt int[N] | gcur int[1] | sums f32[128]
    // | offsets int[N] | cursor int[N] | dinv f32[N] | wbuf ushort[8192] | bucket ushort[E]
    ushort* hb    = (ushort*)d_ws;
    int*   cnt    = (int*)(hb + (size_t)N_NODES * OUT_CH);
    int*   gcur   = cnt + N_NODES;
    float* sums   = (float*)(gcur + 1);
    int*   offs   = (int*)(sums + 128);
    int*   cursor = offs + N_NODES;
    float* dinv   = (float*)(cursor + N_NODES);
    ushort* wbuf  = (ushort*)(dinv + N_NODES);
    ushort* bucket = wbuf + 8192;

    hipMemsetAsync(cnt, 0, (size_t)(N_NODES + 1) * 4, stream);  // cnt + gcur
    count_kernel<<<(E4 + 255) / 256, 256, 0, stream>>>(edst4, cnt, E4);
    alloc_kernel<<<NB_ALLOC + NB_WFRAG, 256, 0, stream>>>(cnt, gcur, offs, cursor, dinv, sums, W, wbuf, N_NODES);
    fill_kernel<<<(E4 + 255) / 256, 256, 0, stream>>>(esrc4, edst4, cursor, bucket, E4);
    gemm_mfma_kernel<<<(N_NODES + 63) / 64, 256, 0, stream>>>(x, wbuf, hb, N_NODES);
    gather_fused_kernel<<<2048, 256, 0, stream>>>(cnt, offs, bucket, dinv, hb, bias, out, sums, N_NODES);
    bn_apply_kernel<<<512, 256, 0, stream>>>((float4*)out, sums, gamma, beta, N_NODES * OUT_CH / 4);
}

// Round 12
// 255.419 us; speedup vs baseline: 1.0538x; 1.0538x over previous
//
#include <hip/hip_runtime.h>
#include <hip/hip_bf16.h>
#include <math.h>

#define N_NODES 50000
#define N_EDGES 800000
#define IN_CH 128
#define OUT_CH 64
#define BN_EPS 1e-5f
#define CAP 32       // slot capacity; P(deg>32) ~ 2e-5 for 800k edges into 50k nodes
#define OVF_MAX 8192 // overflow list capacity (expected usage: a handful)

typedef __attribute__((ext_vector_type(8))) short short8;
typedef __attribute__((ext_vector_type(4))) float f32x4;

__device__ __forceinline__ float bf16u_to_f32(uint u) { return __uint_as_float(u << 16); }

__device__ __forceinline__ ushort f32_to_bf16(float f) {
    uint u = __float_as_uint(f);
    uint r = (u + 0x7fff + ((u >> 16) & 1)) >> 16;  // RNE
    return (ushort)r;
}

// ---------------- one-pass fill: slot[d*CAP+p] = src; overflow -> (d,src) list ----------------
__global__ void fill_slots_kernel(const int4* __restrict__ esrc4, const int4* __restrict__ edst4,
                                  int* __restrict__ cnt, ushort* __restrict__ slot,
                                  int* __restrict__ ovf_cnt, int2* __restrict__ ovf, int E4) {
    int i = blockIdx.x * blockDim.x + threadIdx.x;
    if (i < E4) {
        int4 s = esrc4[i];
        int4 d = edst4[i];
        int p, q;
        p = atomicAdd(&cnt[d.x], 1);
        if (p < CAP) slot[d.x * CAP + p] = (ushort)s.x;
        else { q = atomicAdd(ovf_cnt, 1); if (q < OVF_MAX) ovf[q] = make_int2(d.x, s.x); }
        p = atomicAdd(&cnt[d.y], 1);
        if (p < CAP) slot[d.y * CAP + p] = (ushort)s.y;
        else { q = atomicAdd(ovf_cnt, 1); if (q < OVF_MAX) ovf[q] = make_int2(d.y, s.y); }
        p = atomicAdd(&cnt[d.z], 1);
        if (p < CAP) slot[d.z * CAP + p] = (ushort)s.z;
        else { q = atomicAdd(ovf_cnt, 1); if (q < OVF_MAX) ovf[q] = make_int2(d.z, s.z); }
        p = atomicAdd(&cnt[d.w], 1);
        if (p < CAP) slot[d.w * CAP + p] = (ushort)s.w;
        else { q = atomicAdd(ovf_cnt, 1); if (q < OVF_MAX) ovf[q] = make_int2(d.w, s.w); }
    }
}

// ---------------- prep: dinv = rsqrt(deg+1); zero BN sums ----------------
__global__ void prep_kernel(const int* __restrict__ cnt, float* __restrict__ dinv,
                            float* __restrict__ sums, int N) {
    int i = blockIdx.x * blockDim.x + threadIdx.x;
    if (i < N) dinv[i] = rsqrtf((float)(cnt[i] + 1));
    if (i < 128) sums[i] = 0.0f;
}

// ---------------- MFMA GEMM (R8's LDS version): hb[N,64](bf16) = bf16(x) @ bf16(W) ----------------
#define XPAD 136  // 128 + 8 ushorts
__global__ __launch_bounds__(256) void gemm_mfma_kernel(const float* __restrict__ x,
                                                        const float* __restrict__ W,
                                                        ushort* __restrict__ hb, int N) {
    __shared__ ushort xs[64 * XPAD];
    __shared__ ushort wt[64 * XPAD];   // W^T: wt[n][k]
    int t = threadIdx.x;
    int lane = t & 63;
    int w = t >> 6;
    int nn = lane & 15;
    int quad = lane >> 4;
    int row0 = blockIdx.x * 64;

#pragma unroll
    for (int i = 0; i < 32; ++i) {
        int wlin = t + 256 * i;
        int k = wlin >> 6, n = wlin & 63;
        wt[n * XPAD + k] = f32_to_bf16(W[wlin]);
    }
#pragma unroll
    for (int i = 0; i < 8; ++i) {
        int linear4 = t + 256 * i;
        int r = linear4 >> 5;
        int c4 = linear4 & 31;
        int gr = row0 + r; if (gr >= N) gr = N - 1;
        float4 v = *(const float4*)(x + (size_t)gr * IN_CH + c4 * 4);
        ushort u0 = f32_to_bf16(v.x), u1 = f32_to_bf16(v.y);
        ushort u2 = f32_to_bf16(v.z), u3 = f32_to_bf16(v.w);
        uint2 packed = make_uint2((uint)u0 | ((uint)u1 << 16), (uint)u2 | ((uint)u3 << 16));
        *(uint2*)&xs[r * XPAD + c4 * 4] = packed;
    }
    __syncthreads();

    short8 bfrag[4][4];
#pragma unroll
    for (int t2 = 0; t2 < 4; ++t2)
#pragma unroll
        for (int c = 0; c < 4; ++c)
            bfrag[t2][c] = *(const short8*)&wt[(16 * t2 + nn) * XPAD + 32 * c + quad * 8];

    f32x4 acc[4] = {{0.f, 0.f, 0.f, 0.f}, {0.f, 0.f, 0.f, 0.f},
                    {0.f, 0.f, 0.f, 0.f}, {0.f, 0.f, 0.f, 0.f}};
#pragma unroll
    for (int c = 0; c < 4; ++c) {
        short8 afrag = *(const short8*)&xs[(16 * w + nn) * XPAD + 32 * c + quad * 8];
#pragma unroll
        for (int t2 = 0; t2 < 4; ++t2)
            acc[t2] = __builtin_amdgcn_mfma_f32_16x16x32_bf16(afrag, bfrag[t2][c], acc[t2], 0, 0, 0);
    }

#pragma unroll
    for (int t2 = 0; t2 < 4; ++t2) {
#pragma unroll
        for (int r = 0; r < 4; ++r) {
            int row = row0 + 16 * w + quad * 4 + r;
            if (row < N) hb[(size_t)row * OUT_CH + 16 * t2 + nn] = f32_to_bf16(acc[t2][r]);
        }
    }
}

// ---------------- fused gather: 2 nodes/wave (lanes 0-31 = node A slots, 32-63 = node B) ----------------
// 4-deep unroll x 2 chains = 8 loads in flight; shfl indices wave-uniform.
__global__ __launch_bounds__(256) void gather_fused_kernel(const int* __restrict__ cnt,
                                                           const ushort* __restrict__ slot,
                                                           const float* __restrict__ dinv,
                                                           const ushort* __restrict__ hb,
                                                           const float* __restrict__ bias,
                                                           const int* __restrict__ ovf_cnt,
                                                           const int2* __restrict__ ovf,
                                                           float* __restrict__ out,
                                                           float* __restrict__ sums, int N) {
    int t = threadIdx.x;
    int lane = t & 63;
    int lj = lane & 31;
    int half = lane >> 5;
    int wid = (blockIdx.x * blockDim.x + t) >> 6;
    int nw = (gridDim.x * blockDim.x) >> 6;
    float bias_c = bias[lane];
    int nov = *ovf_cnt; if (nov > OVF_MAX) nov = OVF_MAX;
    float ssum = 0.f, ssq = 0.f;

    for (int d0 = wid; d0 < N; d0 += 2 * nw) {
        int d1 = d0 + nw;
        bool has1 = d1 < N;
        int d1c = has1 ? d1 : d0;
        int m0r = cnt[d0];
        int m1r = has1 ? cnt[d1c] : 0;
        int m0 = m0r < CAP ? m0r : CAP;
        int m1 = m1r < CAP ? m1r : CAP;
        float dd0 = dinv[d0];
        float dd1 = has1 ? dinv[d1c] : 0.f;

        // one slot-row load instruction covers both nodes
        int soff = (half == 0) ? (d0 * CAP + lj) : (d1c * CAP + lj);
        int sv = slot[soff];
        int mv = (half == 0) ? m0 : m1;
        if (lj >= mv) sv = 0;  // clamp unfilled lanes
        float dv = dinv[sv];

        float acc0 = bf16u_to_f32(hb[(size_t)d0 * OUT_CH + lane]) * dd0 * dd0;
        float acc1 = has1 ? bf16u_to_f32(hb[(size_t)d1c * OUT_CH + lane]) * dd1 * dd1 : 0.f;

        int mm = m0 > m1 ? m0 : m1;
        int j = 0;
        for (; j + 3 < mm; j += 4) {
            int a0 = __shfl(sv, j + 0); float u0 = __shfl(dv, j + 0);
            int a1 = __shfl(sv, j + 1); float u1 = __shfl(dv, j + 1);
            int a2 = __shfl(sv, j + 2); float u2 = __shfl(dv, j + 2);
            int a3 = __shfl(sv, j + 3); float u3 = __shfl(dv, j + 3);
            int b0 = __shfl(sv, 32 + j + 0); float q0 = __shfl(dv, 32 + j + 0);
            int b1 = __shfl(sv, 32 + j + 1); float q1 = __shfl(dv, 32 + j + 1);
            int b2 = __shfl(sv, 32 + j + 2); float q2 = __shfl(dv, 32 + j + 2);
            int b3 = __shfl(sv, 32 + j + 3); float q3 = __shfl(dv, 32 + j + 3);
            uint ha0 = hb[(size_t)a0 * OUT_CH + lane];
            uint ha1 = hb[(size_t)a1 * OUT_CH + lane];
            uint ha2 = hb[(size_t)a2 * OUT_CH + lane];
            uint ha3 = hb[(size_t)a3 * OUT_CH + lane];
            uint hc0 = hb[(size_t)b0 * OUT_CH + lane];
            uint hc1 = hb[(size_t)b1 * OUT_CH + lane];
            uint hc2 = hb[(size_t)b2 * OUT_CH + lane];
            uint hc3 = hb[(size_t)b3 * OUT_CH + lane];
            float w0 = (j + 0 < m0) ? u0 * dd0 : 0.f;
            float w1 = (j + 1 < m0) ? u1 * dd0 : 0.f;
            float w2 = (j + 2 < m0) ? u2 * dd0 : 0.f;
            float w3 = (j + 3 < m0) ? u3 * dd0 : 0.f;
            float z0 = (j + 0 < m1) ? q0 * dd1 : 0.f;
            float z1 = (j + 1 < m1) ? q1 * dd1 : 0.f;
            float z2 = (j + 2 < m1) ? q2 * dd1 : 0.f;
            float z3 = (j + 3 < m1) ? q3 * dd1 : 0.f;
            acc0 += bf16u_to_f32(ha0) * w0;
            acc0 += bf16u_to_f32(ha1) * w1;
            acc0 += bf16u_to_f32(ha2) * w2;
            acc0 += bf16u_to_f32(ha3) * w3;
            acc1 += bf16u_to_f32(hc0) * z0;
            acc1 += bf16u_to_f32(hc1) * z1;
            acc1 += bf16u_to_f32(hc2) * z2;
            acc1 += bf16u_to_f32(hc3) * z3;
        }
        for (; j < mm; ++j) {
            int a = __shfl(sv, j); float u = __shfl(dv, j);
            int b = __shfl(sv, 32 + j); float q = __shfl(dv, 32 + j);
            uint ha = hb[(size_t)a * OUT_CH + lane];
            uint hc = hb[(size_t)b * OUT_CH + lane];
            float w = (j < m0) ? u * dd0 : 0.f;
            float z = (j < m1) ? q * dd1 : 0.f;
            acc0 += bf16u_to_f32(ha) * w;
            acc1 += bf16u_to_f32(hc) * z;
        }

        // rare overflow handling (deg > CAP): scan tiny list, wave-uniform compare
        if (m0r > CAP) {
            for (int i = 0; i < nov; ++i) {
                int2 e = ovf[i];
                if (e.x == d0) {
                    float ww = dinv[e.y] * dd0;
                    acc0 += bf16u_to_f32(hb[(size_t)e.y * OUT_CH + lane]) * ww;
                }
            }
        }
        if (has1 && m1r > CAP) {
            for (int i = 0; i < nov; ++i) {
                int2 e = ovf[i];
                if (e.x == d1) {
                    float ww = dinv[e.y] * dd1;
                    acc1 += bf16u_to_f32(hb[(size_t)e.y * OUT_CH + lane]) * ww;
                }
            }
        }

        float v0 = tanhf(acc0 + bias_c);
        out[(size_t)d0 * OUT_CH + lane] = v0;
        ssum += v0; ssq += v0 * v0;
        if (has1) {
            float v1 = tanhf(acc1 + bias_c);
            out[(size_t)d1 * OUT_CH + lane] = v1;
            ssum += v1; ssq += v1 * v1;
        }
    }

    __shared__ float ls[256];
    __shared__ float ls2[256];
    ls[t] = ssum; ls2[t] = ssq;
    __syncthreads();
    if (t < 128) { ls[t] += ls[t + 128]; ls2[t] += ls2[t + 128]; }
    __syncthreads();
    if (t < 64) {
        atomicAdd(&sums[t], ls[t] + ls[t + 64]);
        atomicAdd(&sums[64 + t], ls2[t] + ls2[t + 64]);
    }
}

// ---------------- BN apply in place (float4) ----------------
__global__ __launch_bounds__(256) void bn_apply_kernel(float4* __restrict__ a,
                                                       const float* __restrict__ sums,
                                                       const float* __restrict__ gamma,
                                                       const float* __restrict__ beta, int total4) {
    int c0 = (threadIdx.x * 4) & 63;
    const float invN = 1.0f / (float)N_NODES;
    float4 scale, shift;
    {
        float m0 = sums[c0 + 0] * invN, m1 = sums[c0 + 1] * invN;
        float m2 = sums[c0 + 2] * invN, m3 = sums[c0 + 3] * invN;
        float v0 = sums[64 + c0 + 0] * invN - m0 * m0;
        float v1 = sums[64 + c0 + 1] * invN - m1 * m1;
        float v2 = sums[64 + c0 + 2] * invN - m2 * m2;
        float v3 = sums[64 + c0 + 3] * invN - m3 * m3;
        scale.x = gamma[c0 + 0] * rsqrtf(v0 + BN_EPS);
        scale.y = gamma[c0 + 1] * rsqrtf(v1 + BN_EPS);
        scale.z = gamma[c0 + 2] * rsqrtf(v2 + BN_EPS);
        scale.w = gamma[c0 + 3] * rsqrtf(v3 + BN_EPS);
        shift.x = beta[c0 + 0] - m0 * scale.x;
        shift.y = beta[c0 + 1] - m1 * scale.y;
        shift.z = beta[c0 + 2] - m2 * scale.z;
        shift.w = beta[c0 + 3] - m3 * scale.w;
    }
    int stride = gridDim.x * blockDim.x;
    for (int idx = blockIdx.x * blockDim.x + threadIdx.x; idx < total4; idx += stride) {
        float4 v = a[idx];
        v.x = v.x * scale.x + shift.x;
        v.y = v.y * scale.y + shift.y;
        v.z = v.z * scale.z + shift.z;
        v.w = v.w * scale.w + shift.w;
        a[idx] = v;
    }
}

extern "C" void kernel_launch(void* const* d_in, const int* in_sizes, int n_in,
                              void* d_out, int out_size, void* d_ws, size_t ws_size,
                              hipStream_t stream) {
    const float* x     = (const float*)d_in[0];
    const int*   eidx  = (const int*)d_in[1];   // [2, E] flat: src row then dst row
    const float* W     = (const float*)d_in[2];
    const float* bias  = (const float*)d_in[3];
    const float* gamma = (const float*)d_in[4];
    const float* beta  = (const float*)d_in[5];
    float* out = (float*)d_out;

    const int4* esrc4 = (const int4*)eidx;
    const int4* edst4 = (const int4*)(eidx + N_EDGES);
    const int E4 = N_EDGES / 4;

    // workspace layout:
    // hb ushort[N*64] (6.4MB) | cnt int[N] | ovf_cnt int[1] | pad int[1] | sums f32[128]
    // | dinv f32[N] | slot ushort[N*CAP] (3.2MB) | ovf int2[OVF_MAX]
    ushort* hb     = (ushort*)d_ws;
    int*    cnt    = (int*)(hb + (size_t)N_NODES * OUT_CH);
    int*    ovfc   = cnt + N_NODES;
    float*  sums   = (float*)(ovfc + 2);
    float*  dinv   = sums + 128;
    ushort* slot   = (ushort*)(dinv + N_NODES);
    int2*   ovf    = (int2*)(slot + (size_t)N_NODES * CAP);

    hipMemsetAsync(cnt, 0, (size_t)(N_NODES + 2) * 4, stream);  // cnt + ovf_cnt (+pad)
    fill_slots_kernel<<<(E4 + 255) / 256, 256, 0, stream>>>(esrc4, edst4, cnt, slot, ovfc, ovf, E4);
    prep_kernel<<<(N_NODES + 255) / 256, 256, 0, stream>>>(cnt, dinv, sums, N_NODES);
    gemm_mfma_kernel<<<(N_NODES + 63) / 64, 256, 0, stream>>>(x, W, hb, N_NODES);
    gather_fused_kernel<<<2048, 256, 0, stream>>>(cnt, slot, dinv, hb, bias, ovfc, ovf, out, sums, N_NODES);
    bn_apply_kernel<<<512, 256, 0, stream>>>((float4*)out, sums, gamma, beta, N_NODES * OUT_CH / 4);
}